// Round 6
// baseline (177.172 us; speedup 1.0000x reference)
//
#include <hip/hip_runtime.h>
#include <hip/hip_bf16.h>
#include <stdint.h>
#include <stddef.h>

#define DEVI __device__ __forceinline__

typedef __attribute__((ext_vector_type(8)))  short bf16x8;
typedef __attribute__((ext_vector_type(4)))  float f32x4;
typedef __attribute__((ext_vector_type(16))) float f32x16;
typedef __attribute__((ext_vector_type(2)))  unsigned u32x2;

DEVI unsigned short f2bf(float f) {
    __hip_bfloat16 h = __float2bfloat16(f);   // RNE
    union { __hip_bfloat16 h; unsigned short u; } v; v.h = h; return v.u;
}
DEVI unsigned pk2(float lo, float hi) {
    return (unsigned)f2bf(lo) | ((unsigned)f2bf(hi) << 16);
}
DEVI f32x4 zero4() { f32x4 z; z[0] = z[1] = z[2] = z[3] = 0.f; return z; }
DEVI f32x16 zero16() {
    f32x16 z;
#pragma unroll
    for (int i = 0; i < 16; ++i) z[i] = 0.f;
    return z;
}

// ---------------------------------------------------------------------------
// ws layout:
//   qbf [1024][64][256] bf16 @ 0           natural
//   kbf [2048][64][256] bf16 @ 33554432    natural
//   vbf [2048][64][256] bf16 @ 100663296   natural
//   partial [4][4096][128] f32 @ 167772160
//   pbf [4096][128] bf16 @ 176160768
// ---------------------------------------------------------------------------
// proj structure (per image/block, 256 threads, TWO barriers total):
//   1. stage X fp32->bf16 into LDS [c][p] stride 260 (coalesced loads)
//      + preload W frags (k and v) into regs
//   2. BARRIER; preload A-frags (X) into regs (wave w reads its own
//      columns [w*64,w*64+64) only after this point)
//   3. BARRIER (X region about to be overwritten at different stride)
//   4. k-pass then v-pass, each: MFMA -> pack -> LDS [o][p] stride 264
//      -> per-wave copy-out (columns owned by the wave; no barriers:
//      all LDS deps are within-wave, DS pipeline is in-order per wave)
// ---------------------------------------------------------------------------

#define XS 260   // X staging stride (shorts)
#define OS 264   // output staging stride (shorts; row start 16B-aligned)

DEVI void load_wfrags(const float* __restrict__ W, const float* __restrict__ B,
                      int l15, int lg, bf16x8 (&bf)[4][2], float (&bias)[4]) {
#pragma unroll
    for (int ot = 0; ot < 4; ++ot) {
        const int o = ot * 16 + l15;
        bias[ot] = B[o];
#pragma unroll
        for (int ks = 0; ks < 2; ++ks) {
            const float* wp = W + o * 64 + ks * 32 + lg * 8;
            f32x4 w0 = *(const f32x4*)wp, w1 = *(const f32x4*)(wp + 4);
            bf16x8 a;
#pragma unroll
            for (int j = 0; j < 4; ++j) { a[j] = (short)f2bf(w0[j]); a[4 + j] = (short)f2bf(w1[j]); }
            bf[ot][ks] = a;
        }
    }
}

// one output (16 MFMA tiles): pack into S[o][OS], per-wave coalesced copy-out
DEVI void proj_emit(unsigned short* __restrict__ S, const bf16x8 (&afr)[4][2],
                    const bf16x8 (&bf)[4][2], const float (&bias)[4],
                    int w, int lane, int l15, int lg,
                    unsigned short* __restrict__ og) {
#pragma unroll
    for (int pt = 0; pt < 4; ++pt) {
        const int p = w * 64 + pt * 16 + lg * 4;
#pragma unroll
        for (int ot = 0; ot < 4; ++ot) {
            const int o = ot * 16 + l15;
            f32x4 a1 = zero4();
            a1 = __builtin_amdgcn_mfma_f32_16x16x32_bf16(afr[pt][0], bf[ot][0], a1, 0, 0, 0);
            a1 = __builtin_amdgcn_mfma_f32_16x16x32_bf16(afr[pt][1], bf[ot][1], a1, 0, 0, 0);
            u32x2 sv;
            sv[0] = pk2(a1[0] + bias[ot], a1[1] + bias[ot]);
            sv[1] = pk2(a1[2] + bias[ot], a1[3] + bias[ot]);
            *(u32x2*)(&S[o * OS + p]) = sv;
        }
    }
    // per-wave copy-out of its own columns [w*64, w*64+64): 8 iters,
    // each stores 8 o-rows x 128B contiguous segments
#pragma unroll
    for (int it = 0; it < 8; ++it) {
        const int o  = it * 8 + (lane >> 3);
        const int px = w * 64 + (lane & 7) * 8;
        f32x4 vv = *(const f32x4*)(&S[o * OS + px]);
        *(f32x4*)(og + (size_t)o * 256 + px) = vv;
    }
}

// ============================ proj q ============================
__global__ __launch_bounds__(256) void proj_q_kernel(
    const float* __restrict__ qq, const float* __restrict__ Wq,
    const float* __restrict__ bq, unsigned short* __restrict__ qbf)
{
    __shared__ unsigned short S[64 * OS];
    const int tid = threadIdx.x;
    const int w = tid >> 6, lane = tid & 63;
    const int l15 = lane & 15, lg = lane >> 4;
    const int n = blockIdx.x;
    const float* xg = qq + (size_t)n * 16384;

#pragma unroll
    for (int it = 0; it < 16; ++it) {
        const float* src = xg + it * 1024 + tid * 4;
        f32x4 xv = *(const f32x4*)src;
        u32x2 dd; dd[0] = pk2(xv[0], xv[1]); dd[1] = pk2(xv[2], xv[3]);
        *(u32x2*)(&S[(it * 4 + w) * XS + lane * 4]) = dd;
    }
    bf16x8 bf1[4][2]; float bias1[4];
    load_wfrags(Wq, bq, l15, lg, bf1, bias1);
    __syncthreads();                      // barrier 1: X staged

    bf16x8 afr[4][2];
#pragma unroll
    for (int pt = 0; pt < 4; ++pt) {
        const int p0 = w * 64 + pt * 16;
#pragma unroll
        for (int ks = 0; ks < 2; ++ks) {
            bf16x8 e;
#pragma unroll
            for (int j = 0; j < 8; ++j)
                e[j] = (short)S[(ks * 32 + lg * 8 + j) * XS + p0 + l15];
            afr[pt][ks] = e;
        }
    }
    __syncthreads();                      // barrier 2: X region now dead

    proj_emit(S, afr, bf1, bias1, w, lane, l15, lg, qbf + (size_t)n * 16384);
}

// ============================ proj k + v ============================
__global__ __launch_bounds__(256) void proj_kv_kernel(
    const float* __restrict__ kvg,
    const float* __restrict__ Wk, const float* __restrict__ bk,
    const float* __restrict__ Wv, const float* __restrict__ bv,
    unsigned short* __restrict__ kbf, unsigned short* __restrict__ vbf)
{
    __shared__ unsigned short S[64 * OS];
    const int tid = threadIdx.x;
    const int w = tid >> 6, lane = tid & 63;
    const int l15 = lane & 15, lg = lane >> 4;
    const int n = blockIdx.x;
    const float* xg = kvg + (size_t)n * 16384;

#pragma unroll
    for (int it = 0; it < 16; ++it) {
        const float* src = xg + it * 1024 + tid * 4;
        f32x4 xv = *(const f32x4*)src;
        u32x2 dd; dd[0] = pk2(xv[0], xv[1]); dd[1] = pk2(xv[2], xv[3]);
        *(u32x2*)(&S[(it * 4 + w) * XS + lane * 4]) = dd;
    }
    bf16x8 bf1[4][2], bf2[4][2]; float bias1[4], bias2[4];
    load_wfrags(Wk, bk, l15, lg, bf1, bias1);
    load_wfrags(Wv, bv, l15, lg, bf2, bias2);
    __syncthreads();                      // barrier 1

    bf16x8 afr[4][2];
#pragma unroll
    for (int pt = 0; pt < 4; ++pt) {
        const int p0 = w * 64 + pt * 16;
#pragma unroll
        for (int ks = 0; ks < 2; ++ks) {
            bf16x8 e;
#pragma unroll
            for (int j = 0; j < 8; ++j)
                e[j] = (short)S[(ks * 32 + lg * 8 + j) * XS + p0 + l15];
            afr[pt][ks] = e;
        }
    }
    __syncthreads();                      // barrier 2

    // k then v: both wave-private, no further barriers
    proj_emit(S, afr, bf1, bias1, w, lane, l15, lg, kbf + (size_t)n * 16384);
    proj_emit(S, afr, bf2, bias2, w, lane, l15, lg, vbf + (size_t)n * 16384);
}

// ============================ sim (Q.K^T partials) ============================
// grid 1024 = bh(64) x kq-split(4) x K-split(4); block 128 (2 waves, t-halves)
// XCD-chunked mapping for L2 locality. (round-2 proven version)
__global__ __launch_bounds__(128) void sim_kernel(
    const unsigned short* __restrict__ qbf, const unsigned short* __restrict__ kbf,
    float* __restrict__ partial)
{
    const int tid = threadIdx.x;
    const int w = tid >> 6, lane = tid & 63;
    const int l15 = lane & 15, lg = lane >> 4;
    const int bid = blockIdx.x;
    const int l = (bid & 7) * 128 + (bid >> 3);
    const int kq4 = l & 3, ks = (l >> 2) & 3, bh = l >> 4;
    const int b = bh >> 2, h = bh & 3;

    const unsigned short* qp = qbf + ((size_t)b * 64 + kq4 * 16 + l15) * 16384
                                   + h * 4096 + ks * 1024 + lg * 8;
    const unsigned short* kp = kbf + ((size_t)b * 128 + w * 64 + l15) * 16384
                                   + h * 4096 + ks * 1024 + lg * 8;

    f32x4 acc[4];
#pragma unroll
    for (int tt = 0; tt < 4; ++tt) acc[tt] = zero4();

    for (int kk = 0; kk < 32; ++kk) {
        bf16x8 a = *(const bf16x8*)(qp + kk * 32);
#pragma unroll
        for (int tt = 0; tt < 4; ++tt) {
            bf16x8 bfr = *(const bf16x8*)(kp + (size_t)tt * 16 * 16384 + kk * 32);
            acc[tt] = __builtin_amdgcn_mfma_f32_16x16x32_bf16(a, bfr, acc[tt], 0, 0, 0);
        }
    }

    float* pb = partial + ((size_t)ks * 4096 + (size_t)bh * 64 + kq4 * 16) * 128 + w * 64;
#pragma unroll
    for (int tt = 0; tt < 4; ++tt)
#pragma unroll
        for (int r = 0; r < 4; ++r)
            pb[(lg * 4 + r) * 128 + tt * 16 + l15] = acc[tt][r];
}

// ============================ softmax ============================
__global__ __launch_bounds__(256) void softmax_kernel(
    const float* __restrict__ partial, float* __restrict__ sim_out,
    unsigned short* __restrict__ pbf)
{
    const int tid = threadIdx.x;
    const int w = tid >> 6, lane = tid & 63;
    const int row = blockIdx.x * 4 + w;

    float x0 = 0.f, x1 = 0.f;
#pragma unroll
    for (int s = 0; s < 4; ++s) {
        x0 += partial[((size_t)s * 4096 + row) * 128 + lane];
        x1 += partial[((size_t)s * 4096 + row) * 128 + 64 + lane];
    }
    const float scale = 1.0f / 64.0f;
    x0 *= scale; x1 *= scale;
    float m = fmaxf(x0, x1);
#pragma unroll
    for (int off = 32; off; off >>= 1) m = fmaxf(m, __shfl_xor(m, off));
    float e0 = __expf(x0 - m), e1 = __expf(x1 - m);
    float s = e0 + e1;
#pragma unroll
    for (int off = 32; off; off >>= 1) s += __shfl_xor(s, off);
    float inv = 1.0f / s;
    float p0 = e0 * inv, p1 = e1 * inv;
    sim_out[(size_t)row * 128 + lane]      = p0;
    sim_out[(size_t)row * 128 + 64 + lane] = p1;
    pbf[(size_t)row * 128 + lane]      = f2bf(p0);
    pbf[(size_t)row * 128 + 64 + lane] = f2bf(p1);
}

// ============================ PV (natural V, transpose-on-read) ============================
__global__ __launch_bounds__(256) void pv_kernel(
    const unsigned short* __restrict__ pbf, const unsigned short* __restrict__ vbf,
    float* __restrict__ outp)
{
    const int tid = threadIdx.x;
    const int w = tid >> 6, lane = tid & 63;
    const int l31 = lane & 31, lh = lane >> 5;
    const int bh = blockIdx.x >> 4, cb = blockIdx.x & 15;
    const int b = bh >> 2, h = bh & 3;
    const int ch = h * 16 + cb;
    const int p0 = w * 64;

    const unsigned short* pb = pbf + (size_t)bh * 64 * 128;
    const unsigned short* vb = vbf + (size_t)b * 128 * 16384 + (size_t)ch * 256;

    f32x16 acc00 = zero16(), acc01 = zero16(), acc10 = zero16(), acc11 = zero16();
    for (int kk = 0; kk < 8; ++kk) {
        const int t0 = kk * 16;
        bf16x8 a0 = *(const bf16x8*)(pb + (size_t)l31 * 128 + t0 + lh * 8);
        bf16x8 a1 = *(const bf16x8*)(pb + (size_t)(l31 + 32) * 128 + t0 + lh * 8);
        bf16x8 b0, b1;
#pragma unroll
        for (int j = 0; j < 8; ++j) {
            const unsigned short* vr = vb + (size_t)(t0 + lh * 8 + j) * 16384;
            b0[j] = (short)vr[p0 + l31];
            b1[j] = (short)vr[p0 + 32 + l31];
        }
        acc00 = __builtin_amdgcn_mfma_f32_32x32x16_bf16(a0, b0, acc00, 0, 0, 0);
        acc01 = __builtin_amdgcn_mfma_f32_32x32x16_bf16(a0, b1, acc01, 0, 0, 0);
        acc10 = __builtin_amdgcn_mfma_f32_32x32x16_bf16(a1, b0, acc10, 0, 0, 0);
        acc11 = __builtin_amdgcn_mfma_f32_32x32x16_bf16(a1, b1, acc11, 0, 0, 0);
    }

    float* ob = outp + (size_t)b * 64 * 16384 + (size_t)ch * 256;
#pragma unroll
    for (int r = 0; r < 16; ++r) {
        int kqr = (r & 3) + 8 * (r >> 2) + 4 * lh;
        ob[(size_t)(kqr)      * 16384 + p0 + l31]      = acc00[r];
        ob[(size_t)(kqr)      * 16384 + p0 + 32 + l31] = acc01[r];
        ob[(size_t)(kqr + 32) * 16384 + p0 + l31]      = acc10[r];
        ob[(size_t)(kqr + 32) * 16384 + p0 + 32 + l31] = acc11[r];
    }
}

// ============================ launch ============================
extern "C" void kernel_launch(void* const* d_in, const int* in_sizes, int n_in,
                              void* d_out, int out_size, void* d_ws, size_t ws_size,
                              hipStream_t stream)
{
    const float* qq = (const float*)d_in[0];
    const float* kv = (const float*)d_in[1];
    const float* Wq = (const float*)d_in[2];
    const float* bq = (const float*)d_in[3];
    const float* Wk = (const float*)d_in[4];
    const float* bk = (const float*)d_in[5];
    const float* Wv = (const float*)d_in[6];
    const float* bv = (const float*)d_in[7];

    float* outp    = (float*)d_out;
    float* sim_out = outp + (size_t)16777216;

    char* ws = (char*)d_ws;
    unsigned short* qbf     = (unsigned short*)(ws);
    unsigned short* kbf     = (unsigned short*)(ws + 33554432);
    unsigned short* vbf     = (unsigned short*)(ws + 100663296);
    float*          partial = (float*)         (ws + 167772160);
    unsigned short* pbf     = (unsigned short*)(ws + 176160768);
    (void)in_sizes; (void)n_in; (void)out_size; (void)ws_size;

    proj_kv_kernel<<<dim3(2048), dim3(256), 0, stream>>>(kv, Wk, bk, Wv, bv, kbf, vbf);
    proj_q_kernel <<<dim3(1024), dim3(256), 0, stream>>>(qq, Wq, bq, qbf);
    sim_kernel    <<<dim3(1024), dim3(128), 0, stream>>>(qbf, kbf, partial);
    softmax_kernel<<<dim3(1024), dim3(256), 0, stream>>>(partial, sim_out, pbf);
    pv_kernel     <<<dim3(1024), dim3(256), 0, stream>>>(pbf, vbf, outp);
}

// Round 7
// 172.166 us; speedup vs baseline: 1.0291x; 1.0291x over previous
//
#include <hip/hip_runtime.h>
#include <hip/hip_bf16.h>
#include <stdint.h>
#include <stddef.h>

#define DEVI __device__ __forceinline__

typedef __attribute__((ext_vector_type(8)))  short bf16x8;
typedef __attribute__((ext_vector_type(4)))  float f32x4;
typedef __attribute__((ext_vector_type(16))) float f32x16;
typedef __attribute__((ext_vector_type(2)))  unsigned u32x2;

DEVI unsigned short f2bf(float f) {
    __hip_bfloat16 h = __float2bfloat16(f);   // RNE
    union { __hip_bfloat16 h; unsigned short u; } v; v.h = h; return v.u;
}
DEVI unsigned pk2(float lo, float hi) {
    return (unsigned)f2bf(lo) | ((unsigned)f2bf(hi) << 16);
}
DEVI f32x4 zero4() { f32x4 z; z[0] = z[1] = z[2] = z[3] = 0.f; return z; }
DEVI f32x16 zero16() {
    f32x16 z;
#pragma unroll
    for (int i = 0; i < 16; ++i) z[i] = 0.f;
    return z;
}

// ---------------------------------------------------------------------------
// ws layout:
//   qbf [1024][64][256] bf16 @ 0           natural
//   kbf [2048][64][256] bf16 @ 33554432    natural
//   vbf [2048][64][256] bf16 @ 100663296   natural
//   partial [4][4096][128] f32 @ 167772160
//   pbf [4096][128] bf16 @ 176160768
// ---------------------------------------------------------------------------
// unified proj (3072 blocks: 0..2047 kv-images, 2048..3071 q-images):
//   1. stage X fp32->bf16 into LDS [c][p] stride 260 + preload W1 frags
//   2. BARRIER; preload A-frags (X) into regs
//   3. BARRIER (X region dead)
//   4. emit output 1 (k or q): MFMA -> pack -> LDS [o][264] -> per-wave
//      coalesced dwordx4 copy-out (wave-private columns, no barriers)
//   5. kv-blocks only: reload W-frag regs as Wv (no barrier), emit v
// ---------------------------------------------------------------------------

#define XS 260   // X staging stride (shorts)
#define OS 264   // output staging stride (shorts)

DEVI void load_wfrags(const float* __restrict__ W, const float* __restrict__ B,
                      int l15, int lg, bf16x8 (&bf)[4][2], float (&bias)[4]) {
#pragma unroll
    for (int ot = 0; ot < 4; ++ot) {
        const int o = ot * 16 + l15;
        bias[ot] = B[o];
#pragma unroll
        for (int ks = 0; ks < 2; ++ks) {
            const float* wp = W + o * 64 + ks * 32 + lg * 8;
            f32x4 w0 = *(const f32x4*)wp, w1 = *(const f32x4*)(wp + 4);
            bf16x8 a;
#pragma unroll
            for (int j = 0; j < 4; ++j) { a[j] = (short)f2bf(w0[j]); a[4 + j] = (short)f2bf(w1[j]); }
            bf[ot][ks] = a;
        }
    }
}

// one output (16 MFMA tiles): pack into S[o][OS], per-wave coalesced copy-out
DEVI void proj_emit(unsigned short* __restrict__ S, const bf16x8 (&afr)[4][2],
                    const bf16x8 (&bf)[4][2], const float (&bias)[4],
                    int w, int lane, int l15, int lg,
                    unsigned short* __restrict__ og) {
#pragma unroll
    for (int pt = 0; pt < 4; ++pt) {
        const int p = w * 64 + pt * 16 + lg * 4;
#pragma unroll
        for (int ot = 0; ot < 4; ++ot) {
            const int o = ot * 16 + l15;
            f32x4 a1 = zero4();
            a1 = __builtin_amdgcn_mfma_f32_16x16x32_bf16(afr[pt][0], bf[ot][0], a1, 0, 0, 0);
            a1 = __builtin_amdgcn_mfma_f32_16x16x32_bf16(afr[pt][1], bf[ot][1], a1, 0, 0, 0);
            u32x2 sv;
            sv[0] = pk2(a1[0] + bias[ot], a1[1] + bias[ot]);
            sv[1] = pk2(a1[2] + bias[ot], a1[3] + bias[ot]);
            *(u32x2*)(&S[o * OS + p]) = sv;
        }
    }
    // per-wave copy-out of its own columns [w*64, w*64+64)
#pragma unroll
    for (int it = 0; it < 8; ++it) {
        const int o  = it * 8 + (lane >> 3);
        const int px = w * 64 + (lane & 7) * 8;
        f32x4 vv = *(const f32x4*)(&S[o * OS + px]);
        *(f32x4*)(og + (size_t)o * 256 + px) = vv;
    }
}

// ============================ unified proj ============================
__global__ __launch_bounds__(256) void proj_kernel(
    const float* __restrict__ qq, const float* __restrict__ kvg,
    const float* __restrict__ Wq, const float* __restrict__ bq,
    const float* __restrict__ Wk, const float* __restrict__ bk,
    const float* __restrict__ Wv, const float* __restrict__ bv,
    unsigned short* __restrict__ qbf, unsigned short* __restrict__ kbf,
    unsigned short* __restrict__ vbf)
{
    __shared__ unsigned short S[64 * OS];
    const int tid = threadIdx.x;
    const int w = tid >> 6, lane = tid & 63;
    const int l15 = lane & 15, lg = lane >> 4;
    const int bid = blockIdx.x;
    const bool dual = (bid < 2048);

    const float* xg;
    const float *W1, *B1;
    unsigned short* o1;
    if (dual) {
        xg = kvg + (size_t)bid * 16384;
        W1 = Wk; B1 = bk;
        o1 = kbf + (size_t)bid * 16384;
    } else {
        const int n = bid - 2048;
        xg = qq + (size_t)n * 16384;
        W1 = Wq; B1 = bq;
        o1 = qbf + (size_t)n * 16384;
    }

    // stage X -> LDS bf16 [c][XS]
#pragma unroll
    for (int it = 0; it < 16; ++it) {
        const float* src = xg + it * 1024 + tid * 4;
        f32x4 xv = *(const f32x4*)src;
        u32x2 dd; dd[0] = pk2(xv[0], xv[1]); dd[1] = pk2(xv[2], xv[3]);
        *(u32x2*)(&S[(it * 4 + w) * XS + lane * 4]) = dd;
    }
    bf16x8 bf1[4][2]; float bias1[4];
    load_wfrags(W1, B1, l15, lg, bf1, bias1);
    __syncthreads();                      // barrier 1: X staged

    bf16x8 afr[4][2];
#pragma unroll
    for (int pt = 0; pt < 4; ++pt) {
        const int p0 = w * 64 + pt * 16;
#pragma unroll
        for (int ks = 0; ks < 2; ++ks) {
            bf16x8 e;
#pragma unroll
            for (int j = 0; j < 8; ++j)
                e[j] = (short)S[(ks * 32 + lg * 8 + j) * XS + p0 + l15];
            afr[pt][ks] = e;
        }
    }
    __syncthreads();                      // barrier 2: X region now dead

    proj_emit(S, afr, bf1, bias1, w, lane, l15, lg, o1);

    if (dual) {
        // reload the same frag registers with Wv (global reads, no barrier)
        load_wfrags(Wv, bv, l15, lg, bf1, bias1);
        proj_emit(S, afr, bf1, bias1, w, lane, l15, lg, vbf + (size_t)bid * 16384);
    }
}

// ============================ sim (Q.K^T partials) ============================
// grid 1024 = bh(64) x kq-split(4) x K-split(4); block 128 (2 waves, t-halves)
__global__ __launch_bounds__(128) void sim_kernel(
    const unsigned short* __restrict__ qbf, const unsigned short* __restrict__ kbf,
    float* __restrict__ partial)
{
    const int tid = threadIdx.x;
    const int w = tid >> 6, lane = tid & 63;
    const int l15 = lane & 15, lg = lane >> 4;
    const int bid = blockIdx.x;
    const int l = (bid & 7) * 128 + (bid >> 3);
    const int kq4 = l & 3, ks = (l >> 2) & 3, bh = l >> 4;
    const int b = bh >> 2, h = bh & 3;

    const unsigned short* qp = qbf + ((size_t)b * 64 + kq4 * 16 + l15) * 16384
                                   + h * 4096 + ks * 1024 + lg * 8;
    const unsigned short* kp = kbf + ((size_t)b * 128 + w * 64 + l15) * 16384
                                   + h * 4096 + ks * 1024 + lg * 8;

    f32x4 acc[4];
#pragma unroll
    for (int tt = 0; tt < 4; ++tt) acc[tt] = zero4();

    for (int kk = 0; kk < 32; ++kk) {
        bf16x8 a = *(const bf16x8*)(qp + kk * 32);
#pragma unroll
        for (int tt = 0; tt < 4; ++tt) {
            bf16x8 bfr = *(const bf16x8*)(kp + (size_t)tt * 16 * 16384 + kk * 32);
            acc[tt] = __builtin_amdgcn_mfma_f32_16x16x32_bf16(a, bfr, acc[tt], 0, 0, 0);
        }
    }

    float* pb = partial + ((size_t)ks * 4096 + (size_t)bh * 64 + kq4 * 16) * 128 + w * 64;
#pragma unroll
    for (int tt = 0; tt < 4; ++tt)
#pragma unroll
        for (int r = 0; r < 4; ++r)
            pb[(lg * 4 + r) * 128 + tt * 16 + l15] = acc[tt][r];
}

// ============================ softmax ============================
__global__ __launch_bounds__(256) void softmax_kernel(
    const float* __restrict__ partial, float* __restrict__ sim_out,
    unsigned short* __restrict__ pbf)
{
    const int tid = threadIdx.x;
    const int w = tid >> 6, lane = tid & 63;
    const int row = blockIdx.x * 4 + w;

    float x0 = 0.f, x1 = 0.f;
#pragma unroll
    for (int s = 0; s < 4; ++s) {
        x0 += partial[((size_t)s * 4096 + row) * 128 + lane];
        x1 += partial[((size_t)s * 4096 + row) * 128 + 64 + lane];
    }
    const float scale = 1.0f / 64.0f;
    x0 *= scale; x1 *= scale;
    float m = fmaxf(x0, x1);
#pragma unroll
    for (int off = 32; off; off >>= 1) m = fmaxf(m, __shfl_xor(m, off));
    float e0 = __expf(x0 - m), e1 = __expf(x1 - m);
    float s = e0 + e1;
#pragma unroll
    for (int off = 32; off; off >>= 1) s += __shfl_xor(s, off);
    float inv = 1.0f / s;
    float p0 = e0 * inv, p1 = e1 * inv;
    sim_out[(size_t)row * 128 + lane]      = p0;
    sim_out[(size_t)row * 128 + 64 + lane] = p1;
    pbf[(size_t)row * 128 + lane]      = f2bf(p0);
    pbf[(size_t)row * 128 + 64 + lane] = f2bf(p1);
}

// ============================ PV (natural V, transpose-on-read) ============================
__global__ __launch_bounds__(256) void pv_kernel(
    const unsigned short* __restrict__ pbf, const unsigned short* __restrict__ vbf,
    float* __restrict__ outp)
{
    const int tid = threadIdx.x;
    const int w = tid >> 6, lane = tid & 63;
    const int l31 = lane & 31, lh = lane >> 5;
    const int bh = blockIdx.x >> 4, cb = blockIdx.x & 15;
    const int b = bh >> 2, h = bh & 3;
    const int ch = h * 16 + cb;
    const int p0 = w * 64;

    const unsigned short* pb = pbf + (size_t)bh * 64 * 128;
    const unsigned short* vb = vbf + (size_t)b * 128 * 16384 + (size_t)ch * 256;

    f32x16 acc00 = zero16(), acc01 = zero16(), acc10 = zero16(), acc11 = zero16();
    for (int kk = 0; kk < 8; ++kk) {
        const int t0 = kk * 16;
        bf16x8 a0 = *(const bf16x8*)(pb + (size_t)l31 * 128 + t0 + lh * 8);
        bf16x8 a1 = *(const bf16x8*)(pb + (size_t)(l31 + 32) * 128 + t0 + lh * 8);
        bf16x8 b0, b1;
#pragma unroll
        for (int j = 0; j < 8; ++j) {
            const unsigned short* vr = vb + (size_t)(t0 + lh * 8 + j) * 16384;
            b0[j] = (short)vr[p0 + l31];
            b1[j] = (short)vr[p0 + 32 + l31];
        }
        acc00 = __builtin_amdgcn_mfma_f32_32x32x16_bf16(a0, b0, acc00, 0, 0, 0);
        acc01 = __builtin_amdgcn_mfma_f32_32x32x16_bf16(a0, b1, acc01, 0, 0, 0);
        acc10 = __builtin_amdgcn_mfma_f32_32x32x16_bf16(a1, b0, acc10, 0, 0, 0);
        acc11 = __builtin_amdgcn_mfma_f32_32x32x16_bf16(a1, b1, acc11, 0, 0, 0);
    }

    float* ob = outp + (size_t)b * 64 * 16384 + (size_t)ch * 256;
#pragma unroll
    for (int r = 0; r < 16; ++r) {
        int kqr = (r & 3) + 8 * (r >> 2) + 4 * lh;
        ob[(size_t)(kqr)      * 16384 + p0 + l31]      = acc00[r];
        ob[(size_t)(kqr)      * 16384 + p0 + 32 + l31] = acc01[r];
        ob[(size_t)(kqr + 32) * 16384 + p0 + l31]      = acc10[r];
        ob[(size_t)(kqr + 32) * 16384 + p0 + 32 + l31] = acc11[r];
    }
}

// ============================ launch ============================
extern "C" void kernel_launch(void* const* d_in, const int* in_sizes, int n_in,
                              void* d_out, int out_size, void* d_ws, size_t ws_size,
                              hipStream_t stream)
{
    const float* qq = (const float*)d_in[0];
    const float* kv = (const float*)d_in[1];
    const float* Wq = (const float*)d_in[2];
    const float* bq = (const float*)d_in[3];
    const float* Wk = (const float*)d_in[4];
    const float* bk = (const float*)d_in[5];
    const float* Wv = (const float*)d_in[6];
    const float* bv = (const float*)d_in[7];

    float* outp    = (float*)d_out;
    float* sim_out = outp + (size_t)16777216;

    char* ws = (char*)d_ws;
    unsigned short* qbf     = (unsigned short*)(ws);
    unsigned short* kbf     = (unsigned short*)(ws + 33554432);
    unsigned short* vbf     = (unsigned short*)(ws + 100663296);
    float*          partial = (float*)         (ws + 167772160);
    unsigned short* pbf     = (unsigned short*)(ws + 176160768);
    (void)in_sizes; (void)n_in; (void)out_size; (void)ws_size;

    proj_kernel   <<<dim3(3072), dim3(256), 0, stream>>>(qq, kv, Wq, bq, Wk, bk, Wv, bv,
                                                         qbf, kbf, vbf);
    sim_kernel    <<<dim3(1024), dim3(128), 0, stream>>>(qbf, kbf, partial);
    softmax_kernel<<<dim3(1024), dim3(256), 0, stream>>>(partial, sim_out, pbf);
    pv_kernel     <<<dim3(1024), dim3(256), 0, stream>>>(pbf, vbf, outp);
}